// Round 1
// 279.546 us; speedup vs baseline: 1.5433x; 1.5433x over previous
//
#include <hip/hip_runtime.h>
#include <float.h>

#define LSEQ 1024
#define NCH  8192   // B*H*d = 16*8*64
#define TOPK 13     // int(2*ln(1024))

typedef short bf16x8 __attribute__((ext_vector_type(8)));   // 8 bf16 = 4 VGPRs (MFMA A/B frag)
typedef float f32x16 __attribute__((ext_vector_type(16)));  // MFMA C/D frag

// Per-channel LDS layout (bytes): khi[2176] | klo[2176] | corr[36*32 f32 = 4608]
#define KHI_BYTES 2176u
#define CORR_OFF  4352u
#define CH_STRIDE 8960u

// XOR-swizzle (flip byte-addr bits 4,5 with bits 6,7): keeps 16B blocks intact,
// spreads the 64B-stride window reads across all banks (8 touches/bank = optimal).
__device__ __forceinline__ unsigned swz(unsigned a) { return a ^ ((a >> 2) & 48u); }

// pack bf16(hi16) of two f32 into one word: low half = lo-arg, high half = hi-arg
__device__ __forceinline__ unsigned packhi(unsigned hi, unsigned lo) {
  return __builtin_amdgcn_perm(hi, lo, 0x07060302u);
}
// residual after bf16 truncation (exact in f32)
__device__ __forceinline__ float resid(float x) {
  return x - __uint_as_float(__float_as_uint(x) & 0xffff0000u);
}
__device__ __forceinline__ f32x16 mfma_bf16(bf16x8 a, bf16x8 b, f32x16 c) {
  return __builtin_amdgcn_mfma_f32_32x32x16_bf16(a, b, c, 0, 0, 0);
}

// ---- Tiled transpose: in[b][r][c] -> out[b][c][r] -------------------------
__global__ __launch_bounds__(256) void transpose_rc(const float* __restrict__ in,
                                                    float* __restrict__ out,
                                                    int rows, int cols) {
  __shared__ float tile[32][33];
  int b  = blockIdx.z;
  int r0 = blockIdx.y * 32, c0 = blockIdx.x * 32;
  const float* src = in  + (size_t)b * rows * cols;
  float*       dst = out + (size_t)b * rows * cols;
  int tx = threadIdx.x, ty = threadIdx.y;   // block (32,8)
#pragma unroll
  for (int j = 0; j < 32; j += 8)
    tile[ty + j][tx] = src[(size_t)(r0 + ty + j) * cols + (c0 + tx)];
  __syncthreads();
#pragma unroll
  for (int j = 0; j < 32; j += 8)
    dst[(size_t)(c0 + ty + j) * rows + (r0 + tx)] = tile[tx][ty + j];
}

// ---- Merged Q+K transpose (one launch, z in [0,32)) -----------------------
__global__ __launch_bounds__(256) void transpose_qk(const float* __restrict__ Q,
                                                    const float* __restrict__ K,
                                                    float* __restrict__ qT,
                                                    float* __restrict__ kT) {
  __shared__ float tile[32][33];
  int zz = blockIdx.z;
  const float* in  = (zz < 16) ? Q  : K;
  float*       out = (zz < 16) ? qT : kT;
  int b = zz & 15;
  const int rows = 1024, cols = 512;
  int r0 = blockIdx.y * 32, c0 = blockIdx.x * 32;
  const float* src = in  + (size_t)b * rows * cols;
  float*       dst = out + (size_t)b * rows * cols;
  int tx = threadIdx.x, ty = threadIdx.y;
#pragma unroll
  for (int j = 0; j < 32; j += 8)
    tile[ty + j][tx] = src[(size_t)(r0 + ty + j) * cols + (c0 + tx)];
  __syncthreads();
#pragma unroll
  for (int j = 0; j < 32; j += 8)
    dst[(size_t)(c0 + ty + j) * rows + (r0 + tx)] = tile[tx][ty + j];
}

// ---- MFMA circular correlation + top-13 + softmax -------------------------
// One wave per channel. bf16 hi/lo 3-term split (err ~4e-4 abs, corr sigma~32).
// Per r' in [0,32): D = A(q,32x32) x B_r'(k2e,32x32)^T via 6 mfma_32x32x16_bf16,
// then corr'[a'] = sum_u D[u][(u+a')&31] via 16 ds_bpermute rotate-adds.
// tau = (1024 - (32a'+r')) & 1023.  A and B share the same intra-lane element
// map, so any error in the assumed k-ordering cancels inside the GEMM.
__global__ __launch_bounds__(256) void corr_topk_kernel(const float* __restrict__ qT,
                                                        const float* __restrict__ kT,
                                                        float* __restrict__ wout,
                                                        int* __restrict__ iout) {
  __shared__ __align__(16) unsigned char lds_raw[4 * CH_STRIDE];  // 35840 B
  const int wave = threadIdx.x >> 6, lane = threadIdx.x & 63;
  const int c = blockIdx.x * 4 + wave;
  unsigned char* myh = lds_raw + wave * CH_STRIDE;
  unsigned char* myl = myh + KHI_BYTES;
  float* corrf = (float*)(myh + CORR_OFF);

  // ---- stage k as bf16 hi/lo into swizzled LDS: k2e[x] = k[x & 1023], x<1056
  {
    const float4* k4 = (const float4*)(kT + (size_t)c * LSEQ);
    unsigned sh0 = 0, sh1 = 0, sl0 = 0, sl1 = 0;
#pragma unroll
    for (int j = 0; j < 4; ++j) {
      float4 kv = k4[lane + 64 * j];
      unsigned h0 = packhi(__float_as_uint(kv.y), __float_as_uint(kv.x));
      unsigned h1 = packhi(__float_as_uint(kv.w), __float_as_uint(kv.z));
      unsigned l0 = packhi(__float_as_uint(resid(kv.y)), __float_as_uint(resid(kv.x)));
      unsigned l1 = packhi(__float_as_uint(resid(kv.w)), __float_as_uint(resid(kv.z)));
      unsigned a = 8u * (unsigned)(lane + 64 * j);
      *(uint2*)(myh + swz(a)) = make_uint2(h0, h1);
      *(uint2*)(myl + swz(a)) = make_uint2(l0, l1);
      if (j == 0) { sh0 = h0; sh1 = h1; sl0 = l0; sl1 = l1; }
    }
    if (lane < 8) {  // wrap extension: elems 1024..1055 = k[0..31] (lane's j=0 quad)
      unsigned a = 8u * (unsigned)(256 + lane);
      *(uint2*)(myh + swz(a)) = make_uint2(sh0, sh1);
      *(uint2*)(myl + swz(a)) = make_uint2(sl0, sl1);
    }
  }

  // ---- A fragments: row u = lane&31, k-elem s = 16t + 8H + (2r+h) ---------
  const int row = lane & 31, H = lane >> 5;
  bf16x8 ahi[2], alo[2];
  {
    const float4* q4 = (const float4*)(qT + (size_t)c * LSEQ);
#pragma unroll
    for (int t = 0; t < 2; ++t) {
      float4 qa = q4[8 * row + 4 * t + 2 * H];
      float4 qb = q4[8 * row + 4 * t + 2 * H + 1];
      uint4 hv, lv;
      hv.x = packhi(__float_as_uint(qa.y), __float_as_uint(qa.x));
      hv.y = packhi(__float_as_uint(qa.w), __float_as_uint(qa.z));
      hv.z = packhi(__float_as_uint(qb.y), __float_as_uint(qb.x));
      hv.w = packhi(__float_as_uint(qb.w), __float_as_uint(qb.z));
      lv.x = packhi(__float_as_uint(resid(qa.y)), __float_as_uint(resid(qa.x)));
      lv.y = packhi(__float_as_uint(resid(qa.w)), __float_as_uint(resid(qa.z)));
      lv.z = packhi(__float_as_uint(resid(qb.y)), __float_as_uint(resid(qb.x)));
      lv.w = packhi(__float_as_uint(resid(qb.w)), __float_as_uint(resid(qb.z)));
      ahi[t] = __builtin_bit_cast(bf16x8, hv);
      alo[t] = __builtin_bit_cast(bf16x8, lv);
    }
  }

  // bpermute source-lane addrs: target lane t pulls D[u_r][(t+u_r)&31] from
  // lane ((t+u_r)&31)|(t&32); u_r = (r&3)+8*(r>>2)+4H (verified C-layout rows)
  int addrs[16];
#pragma unroll
  for (int r = 0; r < 16; ++r) {
    int u = (r & 3) + 8 * (r >> 2) + 4 * H;
    addrs[r] = ((((lane & 31) + u) & 31) | (lane & 32)) << 2;
  }

  const f32x16 dz = {};  // zero accumulator seed

  // ---- main loop: r' = 8g + dlt -------------------------------------------
  const unsigned Cb = (unsigned)(64 * row + 16 * H);  // per-lane window base (bytes)
#pragma unroll 1
  for (int g = 0; g < 4; ++g) {
    unsigned base = Cb + 16u * (unsigned)g;
    uint4 A0 = *(const uint4*)(myh + swz(base +  0u));
    uint4 A1 = *(const uint4*)(myh + swz(base + 16u));
    uint4 A2 = *(const uint4*)(myh + swz(base + 32u));
    uint4 A3 = *(const uint4*)(myh + swz(base + 48u));
    uint4 L0 = *(const uint4*)(myl + swz(base +  0u));
    uint4 L1 = *(const uint4*)(myl + swz(base + 16u));
    uint4 L2 = *(const uint4*)(myl + swz(base + 32u));
    uint4 L3 = *(const uint4*)(myl + swz(base + 48u));
    unsigned WH[16] = {A0.x,A0.y,A0.z,A0.w, A1.x,A1.y,A1.z,A1.w,
                       A2.x,A2.y,A2.z,A2.w, A3.x,A3.y,A3.z,A3.w};
    unsigned WL[16] = {L0.x,L0.y,L0.z,L0.w, L1.x,L1.y,L1.z,L1.w,
                       L2.x,L2.y,L2.z,L2.w, L3.x,L3.y,L3.z,L3.w};
#pragma unroll
    for (int dlt = 0; dlt < 8; ++dlt) {
      // B frags: col v = lane&31, elem = k2e[32v + 16t + 8H + (2j+h) + r']
      unsigned bh0[4], bh1[4], bl0[4], bl1[4];
#pragma unroll
      for (int j = 0; j < 4; ++j) {
        const int k0 = j + (dlt >> 1);
        if (dlt & 1) {
          bh0[j] = __builtin_amdgcn_alignbyte(WH[k0 + 1], WH[k0], 2);
          bh1[j] = __builtin_amdgcn_alignbyte(WH[k0 + 9], WH[k0 + 8], 2);
          bl0[j] = __builtin_amdgcn_alignbyte(WL[k0 + 1], WL[k0], 2);
          bl1[j] = __builtin_amdgcn_alignbyte(WL[k0 + 9], WL[k0 + 8], 2);
        } else {
          bh0[j] = WH[k0]; bh1[j] = WH[k0 + 8];
          bl0[j] = WL[k0]; bl1[j] = WL[k0 + 8];
        }
      }
      bf16x8 fbh0 = __builtin_bit_cast(bf16x8, make_uint4(bh0[0], bh0[1], bh0[2], bh0[3]));
      bf16x8 fbh1 = __builtin_bit_cast(bf16x8, make_uint4(bh1[0], bh1[1], bh1[2], bh1[3]));
      bf16x8 fbl0 = __builtin_bit_cast(bf16x8, make_uint4(bl0[0], bl0[1], bl0[2], bl0[3]));
      bf16x8 fbl1 = __builtin_bit_cast(bf16x8, make_uint4(bl1[0], bl1[1], bl1[2], bl1[3]));

      f32x16 d;
      d = mfma_bf16(ahi[0], fbh0, dz);  // hi*hi, K-step 0
      d = mfma_bf16(ahi[1], fbh1, d);   // hi*hi, K-step 1
      d = mfma_bf16(alo[0], fbh0, d);   // lo(q)*hi(k)
      d = mfma_bf16(alo[1], fbh1, d);
      d = mfma_bf16(ahi[0], fbl0, d);   // hi(q)*lo(k)
      d = mfma_bf16(ahi[1], fbl1, d);

      // diagonal reduce: lane t -> sum_u D[u][(u+t)&31] over its half's rows
      float s0 = 0.f, s1 = 0.f;
#pragma unroll
      for (int r = 0; r < 16; r += 2) {
        s0 += __int_as_float(__builtin_amdgcn_ds_bpermute(addrs[r],     __float_as_int(d[r])));
        s1 += __int_as_float(__builtin_amdgcn_ds_bpermute(addrs[r + 1], __float_as_int(d[r + 1])));
      }
      float s = s0 + s1;
      s += __shfl_xor(s, 32);           // combine the two half-row sets
      if (lane < 32) corrf[36 * lane + (8 * g + dlt)] = s;  // [a'][r'], pad 36
    }
  }

  // ---- top-13 (values exact to ~4e-4; idx tracked in tau'-space) ----------
  float acc[16];
  {
    const float* cf = corrf + 36 * (lane >> 1) + 16 * (lane & 1);  // tau' = 16*lane + j
    float4 c0 = *(const float4*)(cf + 0);
    float4 c1 = *(const float4*)(cf + 4);
    float4 c2 = *(const float4*)(cf + 8);
    float4 c3 = *(const float4*)(cf + 12);
    acc[0]=c0.x;  acc[1]=c0.y;  acc[2]=c0.z;  acc[3]=c0.w;
    acc[4]=c1.x;  acc[5]=c1.y;  acc[6]=c1.z;  acc[7]=c1.w;
    acc[8]=c2.x;  acc[9]=c2.y;  acc[10]=c2.z; acc[11]=c2.w;
    acc[12]=c3.x; acc[13]=c3.y; acc[14]=c3.z; acc[15]=c3.w;
  }
  float topv[TOPK]; int topi[TOPK];
  for (int r = 0; r < TOPK; ++r) {
    float m = -FLT_MAX; int mi = 0x7fffffff;
#pragma unroll
    for (int j = 0; j < 16; ++j) {
      int idx = 16 * lane + j;
      if (acc[j] > m || (acc[j] == m && idx < mi)) { m = acc[j]; mi = idx; }
    }
#pragma unroll
    for (int off = 32; off >= 1; off >>= 1) {
      float om = __shfl_xor(m, off);
      int   oi = __shfl_xor(mi, off);
      if (om > m || (om == m && oi < mi)) { m = om; mi = oi; }
    }
    topv[r] = m; topi[r] = mi;
#pragma unroll
    for (int j = 0; j < 16; ++j)        // static-indexed knockout
      acc[j] = (16 * lane + j == mi) ? -FLT_MAX : acc[j];
  }
  float mx = topv[0];
  float wv[TOPK]; float wsum = 0.f;
#pragma unroll
  for (int r = 0; r < TOPK; ++r) { wv[r] = __expf(topv[r] - mx); wsum += wv[r]; }
  float inv = 1.0f / wsum;
  if (lane == 0) {
#pragma unroll
    for (int r = 0; r < TOPK; ++r) {
      wout[(size_t)c * 16 + r] = wv[r] * inv;
      iout[(size_t)c * 16 + r] = (1024 - topi[r]) & 1023;  // tau' -> tau
    }
  }
}

// ---- Time-delay aggregation: outT[c][t] = sum_i w_i * v[min(idx_i+t,L-1)] -
__global__ __launch_bounds__(256) void agg_kernel(const float* __restrict__ vT,
                                                  const float* __restrict__ wbuf,
                                                  const int* __restrict__ ibuf,
                                                  float* __restrict__ outT) {
  __shared__ float v2[2 * LSEQ];     // clamped extension: v2[j>=1024] = v[1023]
  __shared__ float ws[TOPK];
  __shared__ int   is[TOPK];
  int c = blockIdx.x, tid = threadIdx.x;
  const float* v = vT + (size_t)c * LSEQ;
  float last = v[LSEQ - 1];
  float4 vv = ((const float4*)v)[tid];
  ((float4*)v2)[tid]       = vv;
  ((float4*)v2)[tid + 256] = make_float4(last, last, last, last);
  if (tid < TOPK) { ws[tid] = wbuf[(size_t)c * 16 + tid]; is[tid] = ibuf[(size_t)c * 16 + tid]; }
  __syncthreads();
  float a0 = 0.f, a1 = 0.f, a2 = 0.f, a3 = 0.f;
#pragma unroll
  for (int i = 0; i < TOPK; ++i) {
    float wi = ws[i]; int di = is[i];
    a0 += wi * v2[di + tid];
    a1 += wi * v2[di + tid + 256];
    a2 += wi * v2[di + tid + 512];
    a3 += wi * v2[di + tid + 768];
  }
  float* o = outT + (size_t)c * LSEQ + tid;
  o[0] = a0; o[256] = a1; o[512] = a2; o[768] = a3;
}

extern "C" void kernel_launch(void* const* d_in, const int* in_sizes, int n_in,
                              void* d_out, int out_size, void* d_ws, size_t ws_size,
                              hipStream_t stream) {
  const float* Q = (const float*)d_in[0];
  const float* K = (const float*)d_in[1];
  const float* V = (const float*)d_in[2];
  float* out = (float*)d_out;
  float* ws  = (float*)d_ws;
  // ws layout (floats): bufA[8192*1024] | bufB[8192*1024] | w[8192*16] | idx[8192*16]
  float* bufA = ws;
  float* bufB = ws + (size_t)NCH * LSEQ;
  float* wbuf = ws + (size_t)2 * NCH * LSEQ;
  int*   ibuf = (int*)(wbuf + (size_t)NCH * 16);

  dim3 tb(32, 8);
  transpose_qk<<<dim3(16, 32, 32), tb, 0, stream>>>(Q, K, bufA, bufB);    // qT, kT
  corr_topk_kernel<<<NCH / 4, 256, 0, stream>>>(bufA, bufB, wbuf, ibuf);
  transpose_rc<<<dim3(16, 32, 16), tb, 0, stream>>>(V, bufA, 1024, 512);  // vT (qT dead)
  agg_kernel<<<NCH, 256, 0, stream>>>(bufA, wbuf, ibuf, bufB);            // outT (kT dead)
  transpose_rc<<<dim3(32, 16, 16), tb, 0, stream>>>(bufB, out, 512, 1024);
}

// Round 2
// 267.351 us; speedup vs baseline: 1.6137x; 1.0456x over previous
//
#include <hip/hip_runtime.h>
#include <float.h>

#define LSEQ 1024
#define NCH  8192   // B*H*d = 16*8*64
#define TOPK 13     // int(2*ln(1024))

typedef short bf16x8 __attribute__((ext_vector_type(8)));   // 8 bf16 = 4 VGPRs (MFMA A/B frag)
typedef float f32x16 __attribute__((ext_vector_type(16)));  // MFMA C/D frag

// Per-channel LDS layout (dword units):
//   khi[512] @0 | klo[512] @512   (swizzled, circular mod-2048B)
//   qeh[520] @1024 | qel[520] @1544 | qoh[520] @2064 | qol[520] @2584
// total 3104 dwords = 12416 B / channel; 4 channels/block = 49664 B
#define CH_DW 3104

// A-read swizzle: b4 ^= b7, b5 ^= b8 ^ b6.  For byte addr a = 64*row+32*ks+16*H
// (mod 2048) this spreads the 64 lanes' 16B blocks over all 8 bank positions
// (8 accesses/bank = optimal).  Preserves bits 0..3 (16B blocks intact).
__device__ __forceinline__ unsigned swzA(unsigned a) {
  return a ^ ((a >> 3) & 48u) ^ ((a >> 1) & 32u);
}

// pack bf16(hi16) of two f32 into one word: low half = lo-arg, high half = hi-arg
__device__ __forceinline__ unsigned packhi(unsigned hi, unsigned lo) {
  return __builtin_amdgcn_perm(hi, lo, 0x07060302u);
}
// residual after bf16 truncation (exact in f32)
__device__ __forceinline__ float resid(float x) {
  return x - __uint_as_float(__float_as_uint(x) & 0xffff0000u);
}
__device__ __forceinline__ f32x16 mfma_bf16(bf16x8 a, bf16x8 b, f32x16 c) {
  return __builtin_amdgcn_mfma_f32_32x32x16_bf16(a, b, c, 0, 0, 0);
}

// ---- Tiled transpose: in[b][r][c] -> out[b][c][r] -------------------------
__global__ __launch_bounds__(256) void transpose_rc(const float* __restrict__ in,
                                                    float* __restrict__ out,
                                                    int rows, int cols) {
  __shared__ float tile[32][33];
  int b  = blockIdx.z;
  int r0 = blockIdx.y * 32, c0 = blockIdx.x * 32;
  const float* src = in  + (size_t)b * rows * cols;
  float*       dst = out + (size_t)b * rows * cols;
  int tx = threadIdx.x, ty = threadIdx.y;   // block (32,8)
#pragma unroll
  for (int j = 0; j < 32; j += 8)
    tile[ty + j][tx] = src[(size_t)(r0 + ty + j) * cols + (c0 + tx)];
  __syncthreads();
#pragma unroll
  for (int j = 0; j < 32; j += 8)
    dst[(size_t)(c0 + ty + j) * rows + (r0 + tx)] = tile[tx][ty + j];
}

// ---- Merged Q+K transpose (one launch, z in [0,32)) -----------------------
__global__ __launch_bounds__(256) void transpose_qk(const float* __restrict__ Q,
                                                    const float* __restrict__ K,
                                                    float* __restrict__ qT,
                                                    float* __restrict__ kT) {
  __shared__ float tile[32][33];
  int zz = blockIdx.z;
  const float* in  = (zz < 16) ? Q  : K;
  float*       out = (zz < 16) ? qT : kT;
  int b = zz & 15;
  const int rows = 1024, cols = 512;
  int r0 = blockIdx.y * 32, c0 = blockIdx.x * 32;
  const float* src = in  + (size_t)b * rows * cols;
  float*       dst = out + (size_t)b * rows * cols;
  int tx = threadIdx.x, ty = threadIdx.y;
#pragma unroll
  for (int j = 0; j < 32; j += 8)
    tile[ty + j][tx] = src[(size_t)(r0 + ty + j) * cols + (c0 + tx)];
  __syncthreads();
#pragma unroll
  for (int j = 0; j < 32; j += 8)
    dst[(size_t)(c0 + ty + j) * rows + (r0 + tx)] = tile[tx][ty + j];
}

// ---- MFMA circular correlation + top-13 + softmax -------------------------
// One wave per channel.  Single 32x32x1024 GEMM per channel (3-term bf16
// hi/lo split = 192 mfma_32x32x16):
//   D[a][v] = sum_t k[(t+32a) mod 1024] * q[(t - r'(v)) mod 1024]
//           = corr'[32a + r'(v)],   r'(v) = 2*(v&15) + (v>>4)
// Lags land directly in the accumulator: NO diagonal reduce, NO bpermute,
// NO corr LDS round-trip.  tau = (1024 - tau') & 1023 (round-1-validated
// convention).  A/B frags are both "8 consecutive elements at +8H" so the
// intra-lane K-slot map cancels (round-1-validated).
// A-side: aligned swizzled b128 from circular k.  B-side: fine shifts via
// even/odd-parity shifted q copies -> 4B-aligned b32/read2 reads.
__global__ __launch_bounds__(256) void corr_topk_kernel(const float* __restrict__ qT,
                                                        const float* __restrict__ kT,
                                                        float* __restrict__ wout,
                                                        int* __restrict__ iout) {
  __shared__ __align__(16) unsigned lbuf[4 * CH_DW];  // 49664 B
  const int wave = threadIdx.x >> 6, lane = threadIdx.x & 63;
  const int c = blockIdx.x * 4 + wave;
  unsigned* L   = lbuf + wave * CH_DW;
  unsigned* qeh = L + 1024;
  unsigned* qel = L + 1544;
  unsigned* qoh = L + 2064;
  unsigned* qol = L + 2584;

  // ---- stage k as bf16 hi/lo into swizzled circular LDS -------------------
  {
    const float4* k4 = (const float4*)(kT + (size_t)c * LSEQ);
#pragma unroll
    for (int j = 0; j < 4; ++j) {
      float4 kv = k4[lane + 64 * j];
      unsigned h0 = packhi(__float_as_uint(kv.y), __float_as_uint(kv.x));
      unsigned h1 = packhi(__float_as_uint(kv.w), __float_as_uint(kv.z));
      unsigned l0 = packhi(__float_as_uint(resid(kv.y)), __float_as_uint(resid(kv.x)));
      unsigned l1 = packhi(__float_as_uint(resid(kv.w)), __float_as_uint(resid(kv.z)));
      unsigned sw = swzA(8u * (unsigned)(lane + 64 * j)) >> 2;
      *(uint2*)(L + sw)       = make_uint2(h0, h1);   // khi
      *(uint2*)(L + 512 + sw) = make_uint2(l0, l1);   // klo
    }
  }
  // ---- stage q even-parity arrays (+4-dword wrap pads) --------------------
  {
    const float4* q4 = (const float4*)(qT + (size_t)c * LSEQ);
#pragma unroll
    for (int j = 0; j < 4; ++j) {
      float4 qv = q4[lane + 64 * j];
      unsigned h0 = packhi(__float_as_uint(qv.y), __float_as_uint(qv.x));
      unsigned h1 = packhi(__float_as_uint(qv.w), __float_as_uint(qv.z));
      unsigned l0 = packhi(__float_as_uint(resid(qv.y)), __float_as_uint(resid(qv.x)));
      unsigned l1 = packhi(__float_as_uint(resid(qv.w)), __float_as_uint(resid(qv.z)));
      int m = lane + 64 * j;
      *(uint2*)(qeh + 2 * m) = make_uint2(h0, h1);
      *(uint2*)(qel + 2 * m) = make_uint2(l0, l1);
      if (m < 2) {  // pad dwords 512..515 = copy of 0..3
        *(uint2*)(qeh + 512 + 2 * m) = make_uint2(h0, h1);
        *(uint2*)(qel + 512 + 2 * m) = make_uint2(l0, l1);
      }
    }
  }
  // ---- build odd-parity arrays from even (same-wave LDS, in program order)
  {
    uint4 a0 = *(const uint4*)(qeh + 8 * lane);
    uint4 a1 = *(const uint4*)(qeh + 8 * lane + 4);
    unsigned ax = qeh[8 * lane + 8];
    uint4 b0 = *(const uint4*)(qel + 8 * lane);
    uint4 b1 = *(const uint4*)(qel + 8 * lane + 4);
    unsigned bx = qel[8 * lane + 8];
    unsigned wh[9] = {a0.x,a0.y,a0.z,a0.w,a1.x,a1.y,a1.z,a1.w,ax};
    unsigned wl[9] = {b0.x,b0.y,b0.z,b0.w,b1.x,b1.y,b1.z,b1.w,bx};
    unsigned oh[8], ol[8];
#pragma unroll
    for (int i = 0; i < 8; ++i) {
      oh[i] = __builtin_amdgcn_alignbyte(wh[i + 1], wh[i], 2);  // (q[2d+1],q[2d+2])
      ol[i] = __builtin_amdgcn_alignbyte(wl[i + 1], wl[i], 2);
    }
    *(uint4*)(qoh + 8 * lane)     = make_uint4(oh[0],oh[1],oh[2],oh[3]);
    *(uint4*)(qoh + 8 * lane + 4) = make_uint4(oh[4],oh[5],oh[6],oh[7]);
    *(uint4*)(qol + 8 * lane)     = make_uint4(ol[0],ol[1],ol[2],ol[3]);
    *(uint4*)(qol + 8 * lane + 4) = make_uint4(ol[4],ol[5],ol[6],ol[7]);
    if (lane == 0) {  // qo pads 512..515 = qo[0..3]
      *(uint4*)(qoh + 512) = make_uint4(oh[0],oh[1],oh[2],oh[3]);
      *(uint4*)(qol + 512) = make_uint4(ol[0],ol[1],ol[2],ol[3]);
    }
  }

  // ---- main GEMM loop -----------------------------------------------------
  const int row = lane & 31, H = lane >> 5;
  const int rp  = 2 * (row & 15) + (row >> 4);       // fine shift r'(col)
  unsigned e0   = (unsigned)((8 * H - rp) & 1023);   // first q element needed
  const int par = rp & 1;
  unsigned* bH  = par ? qoh : qeh;
  unsigned* bL  = par ? qol : qel;
  unsigned off  = (par ? (e0 - 1) : e0) >> 1;        // dword offset in [0,512)
  unsigned tb   = (unsigned)(64 * row + 16 * H);     // k byte offset (mod 2048)

  f32x16 d = {};
#pragma unroll 4
  for (int ks = 0; ks < 64; ++ks) {
    unsigned sa = swzA(tb);
    uint4 Ah = *(const uint4*)((const unsigned char*)L + sa);          // khi b128
    uint4 Al = *(const uint4*)((const unsigned char*)L + 2048 + sa);   // klo b128
    unsigned w0 = bH[off], w1 = bH[off + 1], w2 = bH[off + 2], w3 = bH[off + 3];
    unsigned x0 = bL[off], x1 = bL[off + 1], x2 = bL[off + 2], x3 = bL[off + 3];
    bf16x8 fah = __builtin_bit_cast(bf16x8, Ah);
    bf16x8 fal = __builtin_bit_cast(bf16x8, Al);
    bf16x8 fbh = __builtin_bit_cast(bf16x8, make_uint4(w0, w1, w2, w3));
    bf16x8 fbl = __builtin_bit_cast(bf16x8, make_uint4(x0, x1, x2, x3));
    d = mfma_bf16(fah, fbh, d);   // hi*hi
    d = mfma_bf16(fal, fbh, d);   // lo(k)*hi(q)
    d = mfma_bf16(fah, fbl, d);   // hi(k)*lo(q)
    tb  = (tb + 32u) & 2047u;
    off = (off + 8u) & 511u;
  }

  // ---- top-13 straight on the accumulator (tau'-space indices) ------------
  // tau'(lane, reg j) = 32*((j&3)+8*(j>>2)) + 128*H + rp   (bijective)
  float acc[16];
#pragma unroll
  for (int i = 0; i < 16; ++i) acc[i] = d[i];
  const int ibase = 128 * H + rp;

  float topv[TOPK]; int topi[TOPK];
  for (int r = 0; r < TOPK; ++r) {
    float m = -FLT_MAX; int mi = 0x7fffffff;
#pragma unroll
    for (int j = 0; j < 16; ++j) {
      int idx = ibase + 32 * ((j & 3) + 8 * (j >> 2));
      if (acc[j] > m || (acc[j] == m && idx < mi)) { m = acc[j]; mi = idx; }
    }
#pragma unroll
    for (int offx = 32; offx >= 1; offx >>= 1) {
      float om = __shfl_xor(m, offx);
      int   oi = __shfl_xor(mi, offx);
      if (om > m || (om == m && oi < mi)) { m = om; mi = oi; }
    }
    topv[r] = m; topi[r] = mi;
#pragma unroll
    for (int j = 0; j < 16; ++j)        // static-indexed knockout
      acc[j] = (ibase + 32 * ((j & 3) + 8 * (j >> 2)) == mi) ? -FLT_MAX : acc[j];
  }
  float mx = topv[0];
  float wv[TOPK]; float wsum = 0.f;
#pragma unroll
  for (int r = 0; r < TOPK; ++r) { wv[r] = __expf(topv[r] - mx); wsum += wv[r]; }
  float inv = 1.0f / wsum;
  if (lane == 0) {
#pragma unroll
    for (int r = 0; r < TOPK; ++r) {
      wout[(size_t)c * 16 + r] = wv[r] * inv;
      iout[(size_t)c * 16 + r] = (1024 - topi[r]) & 1023;  // tau' -> tau
    }
  }
}

// ---- Time-delay aggregation: outT[c][t] = sum_i w_i * v[min(idx_i+t,L-1)] -
__global__ __launch_bounds__(256) void agg_kernel(const float* __restrict__ vT,
                                                  const float* __restrict__ wbuf,
                                                  const int* __restrict__ ibuf,
                                                  float* __restrict__ outT) {
  __shared__ float v2[2 * LSEQ];     // clamped extension: v2[j>=1024] = v[1023]
  __shared__ float ws[TOPK];
  __shared__ int   is[TOPK];
  int c = blockIdx.x, tid = threadIdx.x;
  const float* v = vT + (size_t)c * LSEQ;
  float last = v[LSEQ - 1];
  float4 vv = ((const float4*)v)[tid];
  ((float4*)v2)[tid]       = vv;
  ((float4*)v2)[tid + 256] = make_float4(last, last, last, last);
  if (tid < TOPK) { ws[tid] = wbuf[(size_t)c * 16 + tid]; is[tid] = ibuf[(size_t)c * 16 + tid]; }
  __syncthreads();
  float a0 = 0.f, a1 = 0.f, a2 = 0.f, a3 = 0.f;
#pragma unroll
  for (int i = 0; i < TOPK; ++i) {
    float wi = ws[i]; int di = is[i];
    a0 += wi * v2[di + tid];
    a1 += wi * v2[di + tid + 256];
    a2 += wi * v2[di + tid + 512];
    a3 += wi * v2[di + tid + 768];
  }
  float* o = outT + (size_t)c * LSEQ + tid;
  o[0] = a0; o[256] = a1; o[512] = a2; o[768] = a3;
}

extern "C" void kernel_launch(void* const* d_in, const int* in_sizes, int n_in,
                              void* d_out, int out_size, void* d_ws, size_t ws_size,
                              hipStream_t stream) {
  const float* Q = (const float*)d_in[0];
  const float* K = (const float*)d_in[1];
  const float* V = (const float*)d_in[2];
  float* out = (float*)d_out;
  float* ws  = (float*)d_ws;
  // ws layout (floats): bufA[8192*1024] | bufB[8192*1024] | w[8192*16] | idx[8192*16]
  float* bufA = ws;
  float* bufB = ws + (size_t)NCH * LSEQ;
  float* wbuf = ws + (size_t)2 * NCH * LSEQ;
  int*   ibuf = (int*)(wbuf + (size_t)NCH * 16);

  dim3 tb(32, 8);
  transpose_qk<<<dim3(16, 32, 32), tb, 0, stream>>>(Q, K, bufA, bufB);    // qT, kT
  corr_topk_kernel<<<NCH / 4, 256, 0, stream>>>(bufA, bufB, wbuf, ibuf);
  transpose_rc<<<dim3(16, 32, 16), tb, 0, stream>>>(V, bufA, 1024, 512);  // vT (qT dead)
  agg_kernel<<<NCH, 256, 0, stream>>>(bufA, wbuf, ibuf, bufB);            // outT (kT dead)
  transpose_rc<<<dim3(32, 16, 16), tb, 0, stream>>>(bufB, out, 512, 1024);
}